// Round 1
// baseline (126.903 us; speedup 1.0000x reference)
//
#include <hip/hip_runtime.h>
#include <math.h>

#define NFFT 1024
#define N2   512
#define NF   513   // NFFT/2 + 1

struct cplx { float x, y; };
__device__ inline cplx cadd(cplx a, cplx b){ return {a.x+b.x, a.y+b.y}; }
__device__ inline cplx csub(cplx a, cplx b){ return {a.x-b.x, a.y-b.y}; }
__device__ inline cplx cmul(cplx a, cplx b){ return {a.x*b.x - a.y*b.y, a.x*b.y + a.y*b.x}; }

// ---------------- Kernel 1: per-row FFT + PSD + row stats + batch-PSD accum ----------------
__global__ __launch_bounds__(256)
void k1(const float* __restrict__ preds, const int* __restrict__ FsPtr,
        float* __restrict__ gpsd, float* __restrict__ gband, float* __restrict__ gsparse,
        int B, int rpb)
{
    __shared__ cplx bufA[N2];
    __shared__ cplx bufB[N2];
    __shared__ cplx tw[256];          // exp(-2*pi*i*j/512), j in [0,256)
    __shared__ float psd_s[NF];
    __shared__ float bacc[NF];        // per-block batch-psd accumulator
    __shared__ float rtp[4], rip[4], rmv[4];
    __shared__ int   rmi[4];
    __shared__ float accBand, accSparse;

    const int tid = threadIdx.x;
    const int Fs  = *FsPtr;

    // band parameters (uniform grid => argmin == rint(target/step))
    const double step = (double)Fs * 0.5 / (double)(NF - 1);
    const int left  = (int)rint((40.0 / 60.0) / step);
    const int right = (int)rint((180.0 / 60.0) / step);
    const double binw = (double)Fs * 0.5 / (double)NF;
    int delta = (int)rint((6.0 / 60.0) / binw);
    if (delta < 1) delta = 1;

    // twiddle table
    {
        float s, c;
        sincosf(-2.0f * (float)M_PI * (float)tid / (float)N2, &s, &c);
        tw[tid] = {c, s};
    }
    bacc[tid] = 0.f; bacc[tid + 256] = 0.f;
    if (tid == 0) { bacc[512] = 0.f; accBand = 0.f; accSparse = 0.f; }
    __syncthreads();

    for (int r = 0; r < rpb; ++r) {
        const int row = blockIdx.x * rpb + r;     // uniform across block
        if (row >= B) break;

        // load 1024 floats, pack into 512 complex: z[n] = (x[2n], x[2n+1])
        const float4* src4 = (const float4*)(preds + (size_t)row * NFFT);
        float4 v = src4[tid];
        bufA[2 * tid]     = {v.x, v.y};
        bufA[2 * tid + 1] = {v.z, v.w};
        __syncthreads();

        // 512-point complex Stockham FFT (DIF, auto-sort), 9 radix-2 stages
        cplx* s_ = bufA; cplx* d_ = bufB;
        #pragma unroll
        for (int ls = 0; ls < 9; ++ls) {
            const int sS = 1 << ls;
            const int q  = tid & (sS - 1);
            const int p  = tid >> ls;
            cplx a = s_[tid];
            cplx b = s_[tid + 256];
            cplx w = tw[p << ls];
            const int o = (p << (ls + 1)) + q;
            d_[o]      = cadd(a, b);
            d_[o + sS] = cmul(csub(a, b), w);
            __syncthreads();
            cplx* t = s_; s_ = d_; d_ = t;
        }
        // result now in s_ (naturally ordered Z[0..511])

        // real-FFT unpack -> psd bins
        auto psdAt = [&](int k) -> float {
            const int k1i = k & (N2 - 1);
            const int k2i = (N2 - k) & (N2 - 1);
            cplx Zk = s_[k1i];
            cplx Zr = s_[k2i];
            float Ex = 0.5f * (Zk.x + Zr.x);
            float Ey = 0.5f * (Zk.y - Zr.y);
            float Ox = 0.5f * (Zk.y + Zr.y);
            float Oy = -0.5f * (Zk.x - Zr.x);
            float sw, cw;
            __sincosf(-(float)M_PI * (float)k / (float)N2, &sw, &cw);
            float Xx = Ex + cw * Ox - sw * Oy;
            float Xy = Ey + cw * Oy + sw * Ox;
            return Xx * Xx + Xy * Xy;
        };
        const float p0 = psdAt(tid);
        const float p1 = psdAt(tid + 256);
        const float p2 = (tid == 0) ? psdAt(512) : 0.f;
        psd_s[tid] = p0; psd_s[tid + 256] = p1;
        if (tid == 0) psd_s[512] = p2;
        bacc[tid] += p0; bacc[tid + 256] += p1;
        if (tid == 0) bacc[512] += p2;

        // per-thread partials: total, in-band sum, in-band argmax (first-index ties)
        float tp = p0 + p1 + p2;
        float ip = 0.f;
        float mv = -1.f; int mi = 0x7fffffff;
        if (tid >= left && tid < right) { ip += p0; if (p0 > mv) { mv = p0; mi = tid; } }
        const int kb = tid + 256;
        if (kb >= left && kb < right)  { ip += p1; if (p1 > mv) { mv = p1; mi = kb; } }

        // wave (64) reduce
        #pragma unroll
        for (int off = 32; off > 0; off >>= 1) {
            tp += __shfl_down(tp, off);
            ip += __shfl_down(ip, off);
            float ov = __shfl_down(mv, off);
            int   oi = __shfl_down(mi, off);
            if (ov > mv || (ov == mv && oi < mi)) { mv = ov; mi = oi; }
        }
        const int wid = tid >> 6, lane = tid & 63;
        if (lane == 0) { rtp[wid] = tp; rip[wid] = ip; rmv[wid] = mv; rmi[wid] = mi; }
        __syncthreads();
        if (tid == 0) {
            for (int w = 1; w < 4; ++w) {
                tp += rtp[w]; ip += rip[w];
                if (rmv[w] > mv || (rmv[w] == mv && rmi[w] < mi)) { mv = rmv[w]; mi = rmi[w]; }
            }
            const int peak = mi;
            const int lo = max(left, peak - delta);
            const int hi = min(right, peak + delta);
            float nearS = 0.f;
            for (int k = lo; k < hi; ++k) nearS += psd_s[k];
            const float band   = (tp - ip) / (1e-8f + tp);
            const float sparse = (ip - nearS) / (ip + 1e-8f * (float)(right - left));
            accBand   += band;
            accSparse += sparse;
        }
        __syncthreads();
    }

    // flush per-block accumulators
    atomicAdd(&gpsd[tid],       bacc[tid]);
    atomicAdd(&gpsd[tid + 256], bacc[tid + 256]);
    if (tid == 0) {
        atomicAdd(&gpsd[512], bacc[512]);
        atomicAdd(gband,   accBand);
        atomicAdd(gsparse, accSparse);
    }
}

// ---------------- Kernel 2: variance loss + final combine ----------------
__global__ __launch_bounds__(256)
void k2(const float* __restrict__ gpsd, const float* __restrict__ gband,
        const float* __restrict__ gsparse, const int* __restrict__ FsPtr,
        float* __restrict__ out, int B)
{
    __shared__ float a[NF];
    __shared__ float b[NF];
    __shared__ float red[4];

    const int tid = threadIdx.x;
    const int Fs  = *FsPtr;

    a[tid] = gpsd[tid]; a[tid + 256] = gpsd[tid + 256];
    if (tid == 0) a[512] = gpsd[512];
    __syncthreads();

    // total
    float sp = a[tid] + a[tid + 256] + (tid == 0 ? a[512] : 0.f);
    #pragma unroll
    for (int off = 32; off > 0; off >>= 1) sp += __shfl_down(sp, off);
    const int wid = tid >> 6, lane = tid & 63;
    if (lane == 0) red[wid] = sp;
    __syncthreads();
    const float S = red[0] + red[1] + red[2] + red[3];
    const float inv = 1.f / (1e-8f + S);
    a[tid] *= inv; a[tid + 256] *= inv;
    if (tid == 0) a[512] *= inv;
    __syncthreads();

    // inclusive scan (Hillis-Steele) over 513 entries
    float* pa = a; float* pb = b;
    for (int off = 1; off < NF; off <<= 1) {
        for (int i = tid; i < NF; i += 256)
            pb[i] = pa[i] + (i >= off ? pa[i - off] : 0.f);
        __syncthreads();
        float* t = pa; pa = pb; pb = t;
    }

    // variance loss vs uniform CDF
    const double fs2 = (double)Fs * 0.5;
    const double stp = fs2 / (double)(NF - 1);
    float vp = 0.f;
    for (int i = tid; i < NF; i += 256) {
        float Q = fminf(fmaxf(pa[i], 0.f), 1.f);
        float P = (float)((double)i * stp) / (float)fs2;
        P = fminf(fmaxf(P, 0.f), 1.f);
        const float d = P - Q;
        vp += d * d;
    }
    #pragma unroll
    for (int off = 32; off > 0; off >>= 1) vp += __shfl_down(vp, off);
    if (lane == 0) red[wid] = vp;
    __syncthreads();
    if (tid == 0) {
        const float var = (red[0] + red[1] + red[2] + red[3]) / (float)NF;
        out[0] = (*gband) / (float)B + (*gsparse) / (float)B + var;
    }
}

extern "C" void kernel_launch(void* const* d_in, const int* in_sizes, int n_in,
                              void* d_out, int out_size, void* d_ws, size_t ws_size,
                              hipStream_t stream)
{
    const float* preds = (const float*)d_in[0];
    const int*   Fs    = (const int*)d_in[1];
    const int B = in_sizes[0] / NFFT;

    float* gpsd    = (float*)d_ws;
    float* gband   = gpsd + NF;
    float* gsparse = gband + 1;

    hipMemsetAsync(d_ws, 0, (NF + 2) * sizeof(float), stream);

    int nblocks = 2048;
    if (nblocks > B) nblocks = B;
    const int rpb = (B + nblocks - 1) / nblocks;

    hipLaunchKernelGGL(k1, dim3(nblocks), dim3(256), 0, stream,
                       preds, Fs, gpsd, gband, gsparse, B, rpb);
    hipLaunchKernelGGL(k2, dim3(1), dim3(256), 0, stream,
                       gpsd, gband, gsparse, Fs, (float*)d_out, B);
}

// Round 2
// 85.376 us; speedup vs baseline: 1.4864x; 1.4864x over previous
//
#include <hip/hip_runtime.h>
#include <math.h>

#define NFFT 1024
#define N2   512
#define NF   513   // NFFT/2 + 1

__device__ inline float2 cadd2(float2 a, float2 b){ return make_float2(a.x+b.x, a.y+b.y); }
__device__ inline float2 csub2(float2 a, float2 b){ return make_float2(a.x-b.x, a.y-b.y); }
__device__ inline float2 cmul2(float2 a, float2 b){ return make_float2(a.x*b.x - a.y*b.y, a.x*b.y + a.y*b.x); }

__device__ inline float2 shflxor2(float2 v, int m){
    return make_float2(__shfl_xor(v.x, m), __shfl_xor(v.y, m));
}
__device__ inline float2 shflidx2(float2 v, int idx){
    return make_float2(__shfl(v.x, idx), __shfl(v.y, idx));
}
__device__ inline int brev6(int x){ return (int)(__brev((unsigned)x) >> 26); }

// ---------------- Kernel 1: wave-per-row register FFT + PSD + stats ----------------
__global__ __launch_bounds__(256)
void k1(const float* __restrict__ preds, const int* __restrict__ FsPtr,
        float* __restrict__ gpsd, float* __restrict__ gband, float* __restrict__ gsparse,
        int B, int rpw)
{
    __shared__ float bacc[NF];
    __shared__ float bBand, bSparse;

    const int tid  = threadIdx.x;
    const int lane = tid & 63;
    const int wid  = tid >> 6;
    const int Fs   = *FsPtr;

    // band parameters (uniform grid => argmin == rint(target/step))
    const double stepd = (double)Fs * 0.5 / (double)(NF - 1);
    const int left  = (int)rint((40.0 / 60.0) / stepd);
    const int right = (int)rint((180.0 / 60.0) / stepd);
    const double binw = (double)Fs * 0.5 / (double)NF;
    int delta = (int)rint((6.0 / 60.0) / binw);
    if (delta < 1) delta = 1;

    // zero block accumulators
    bacc[tid] = 0.f; bacc[tid + 256] = 0.f;
    if (tid == 0) { bacc[512] = 0.f; bBand = 0.f; bSparse = 0.f; }
    __syncthreads();

    // ---- row-invariant per-lane constants ----
    const int K  = brev6(lane);     // k2 for this lane after DIF
    const int kk = K << 3;          // first output bin held by this lane
    const float PIF = 3.14159265358979323846f;

    // step-2 twiddles: W_512^{lane*r}
    float2 tw2[8];
    #pragma unroll
    for (int r = 1; r < 8; ++r) {
        float s, c;
        sincosf(-2.0f * PIF * (float)(lane * r) / 512.0f, &s, &c);
        tw2[r] = make_float2(c, s);
    }
    // cross-lane DIF stage twiddles (identity on low-half lanes)
    float2 wS[6];
    #pragma unroll
    for (int s = 0; s < 6; ++s) {
        const int m = 32 >> s;
        if (lane & m) {
            float sn, cs;
            sincosf(-2.0f * PIF * (float)(lane & (m - 1)) / (float)(2 * m), &sn, &cs);
            wS[s] = make_float2(cs, sn);
        } else {
            wS[s] = make_float2(1.f, 0.f);
        }
    }
    // real-unpack twiddles exp(-i*pi*k/512), k = kk + r
    float2 uw[8];
    #pragma unroll
    for (int r = 0; r < 8; ++r) {
        float s, c;
        sincosf(-PIF * (float)(kk + r) / 512.0f, &s, &c);
        uw[r] = make_float2(c, s);
    }
    // partner lane for reg 0: holds Z[(512 - 8K) mod 512]
    const int p0idx = brev6((64 - K) & 63);

    // per-wave accumulators (registers)
    float baccR[8] = {0.f,0.f,0.f,0.f,0.f,0.f,0.f,0.f};
    float bacc512 = 0.f;
    float accB = 0.f, accS = 0.f;

    const int gw   = blockIdx.x * 4 + wid;
    const int row0 = gw * rpw;

    for (int rr = 0; rr < rpw; ++rr) {
        const int row = row0 + rr;
        if (row >= B) break;

        // load row: z[r] = (x[2n], x[2n+1]), n = 64*r + lane  (coalesced 8B/lane)
        const float2* src = (const float2*)(preds + (size_t)row * NFFT);
        float2 z[8];
        #pragma unroll
        for (int r = 0; r < 8; ++r) z[r] = src[(r << 6) + lane];

        // ---- step 1: 8-point DIT FFT in registers (natural-order output) ----
        float2 c0 = cadd2(z[0], z[4]), c1 = csub2(z[0], z[4]);
        float2 c2 = cadd2(z[2], z[6]), c3 = csub2(z[2], z[6]);
        float2 c4 = cadd2(z[1], z[5]), c5 = csub2(z[1], z[5]);
        float2 c6 = cadd2(z[3], z[7]), c7 = csub2(z[3], z[7]);
        float2 mi3 = make_float2(c3.y, -c3.x);               // -i*c3
        float2 mi7 = make_float2(c7.y, -c7.x);               // -i*c7
        float2 d0 = cadd2(c0, c2), d2 = csub2(c0, c2);
        float2 d1 = cadd2(c1, mi3), d3 = csub2(c1, mi3);
        float2 d4 = cadd2(c4, c6), d6 = csub2(c4, c6);
        float2 d5 = cadd2(c5, mi7), d7 = csub2(c5, mi7);
        const float S2 = 0.70710678118654752f;
        float2 w1d5 = make_float2(S2 * (d5.x + d5.y), S2 * (d5.y - d5.x));   // W8^1 * d5
        float2 mid6 = make_float2(d6.y, -d6.x);                               // -i*d6
        float2 w3d7 = make_float2(S2 * (d7.y - d7.x), -S2 * (d7.x + d7.y));  // W8^3 * d7
        z[0] = cadd2(d0, d4);  z[4] = csub2(d0, d4);
        z[1] = cadd2(d1, w1d5); z[5] = csub2(d1, w1d5);
        z[2] = cadd2(d2, mid6); z[6] = csub2(d2, mid6);
        z[3] = cadd2(d3, w3d7); z[7] = csub2(d3, w3d7);

        // ---- step 2: twiddle W_512^{lane*r} ----
        #pragma unroll
        for (int r = 1; r < 8; ++r) z[r] = cmul2(z[r], tw2[r]);

        // ---- step 3: 64-point DIF FFT across lanes via shfl_xor ----
        #pragma unroll
        for (int s = 0; s < 6; ++s) {
            const int m = 32 >> s;
            const bool hi = (lane & m) != 0;
            #pragma unroll
            for (int r = 0; r < 8; ++r) {
                float2 p = shflxor2(z[r], m);
                float2 t = hi ? csub2(p, z[r]) : cadd2(z[r], p);
                z[r] = cmul2(t, wS[s]);   // wS = (1,0) on low lanes -> exact
            }
        }
        // lane holds Z[kk + r], kk = 8*brev6(lane)

        // ---- real-FFT unpack + PSD, fully in registers ----
        float2 zr[8];
        zr[0] = shflidx2(z[0], p0idx);
        #pragma unroll
        for (int r = 1; r < 8; ++r) zr[r] = shflxor2(z[8 - r], 63);

        float P[8];
        #pragma unroll
        for (int r = 0; r < 8; ++r) {
            float Ex = 0.5f * (z[r].x + zr[r].x);
            float Ey = 0.5f * (z[r].y - zr[r].y);
            float Ox = 0.5f * (z[r].y + zr[r].y);
            float Oy = -0.5f * (z[r].x - zr[r].x);
            float Xx = Ex + uw[r].x * Ox - uw[r].y * Oy;
            float Xy = Ey + uw[r].x * Oy + uw[r].y * Ox;
            P[r] = Xx * Xx + Xy * Xy;
        }
        float p512 = 0.f;
        if (lane == 0) { float t = z[0].x - z[0].y; p512 = t * t; }  // X[512] = ReZ0 - ImZ0

        // ---- per-row stats ----
        float tp = p512;
        float ip = 0.f, mv = -1.f; int mi_ = 0x7fffffff;
        #pragma unroll
        for (int r = 0; r < 8; ++r) {
            const int k = kk + r;
            tp += P[r];
            if (k >= left && k < right) {
                ip += P[r];
                if (P[r] > mv) { mv = P[r]; mi_ = k; }
            }
        }
        #pragma unroll
        for (int off = 1; off < 64; off <<= 1) {
            tp += __shfl_xor(tp, off);
            ip += __shfl_xor(ip, off);
            float ov = __shfl_xor(mv, off);
            int   oi = __shfl_xor(mi_, off);
            if (ov > mv || (ov == mv && oi < mi_)) { mv = ov; mi_ = oi; }
        }
        const int peak = mi_;
        const int lo  = max(left, peak - delta);
        const int hi2 = min(right, peak + delta);
        float ns = 0.f;
        #pragma unroll
        for (int r = 0; r < 8; ++r) { const int k = kk + r; if (k >= lo && k < hi2) ns += P[r]; }
        #pragma unroll
        for (int off = 1; off < 64; off <<= 1) ns += __shfl_xor(ns, off);

        accB += (tp - ip) / (1e-8f + tp);
        accS += (ip - ns) / (ip + 1e-8f * (float)(right - left));

        #pragma unroll
        for (int r = 0; r < 8; ++r) baccR[r] += P[r];
        bacc512 += p512;
    }

    // ---- flush: wave regs -> block LDS -> global atomics ----
    #pragma unroll
    for (int r = 0; r < 8; ++r) atomicAdd(&bacc[kk + r], baccR[r]);
    if (lane == 0) {
        atomicAdd(&bacc[512], bacc512);
        atomicAdd(&bBand, accB);
        atomicAdd(&bSparse, accS);
    }
    __syncthreads();
    atomicAdd(&gpsd[tid],       bacc[tid]);
    atomicAdd(&gpsd[tid + 256], bacc[tid + 256]);
    if (tid == 0) {
        atomicAdd(&gpsd[512], bacc[512]);
        atomicAdd(gband,   bBand);
        atomicAdd(gsparse, bSparse);
    }
}

// ---------------- Kernel 2: variance loss + final combine ----------------
__global__ __launch_bounds__(256)
void k2(const float* __restrict__ gpsd, const float* __restrict__ gband,
        const float* __restrict__ gsparse, const int* __restrict__ FsPtr,
        float* __restrict__ out, int B)
{
    __shared__ float a[NF];
    __shared__ float b[NF];
    __shared__ float red[4];

    const int tid = threadIdx.x;
    const int Fs  = *FsPtr;

    a[tid] = gpsd[tid]; a[tid + 256] = gpsd[tid + 256];
    if (tid == 0) a[512] = gpsd[512];
    __syncthreads();

    float sp = a[tid] + a[tid + 256] + (tid == 0 ? a[512] : 0.f);
    #pragma unroll
    for (int off = 32; off > 0; off >>= 1) sp += __shfl_down(sp, off);
    const int wid = tid >> 6, lane = tid & 63;
    if (lane == 0) red[wid] = sp;
    __syncthreads();
    const float S = red[0] + red[1] + red[2] + red[3];
    const float inv = 1.f / (1e-8f + S);
    a[tid] *= inv; a[tid + 256] *= inv;
    if (tid == 0) a[512] *= inv;
    __syncthreads();

    float* pa = a; float* pb = b;
    for (int off = 1; off < NF; off <<= 1) {
        for (int i = tid; i < NF; i += 256)
            pb[i] = pa[i] + (i >= off ? pa[i - off] : 0.f);
        __syncthreads();
        float* t = pa; pa = pb; pb = t;
    }

    const double fs2 = (double)Fs * 0.5;
    const double stp = fs2 / (double)(NF - 1);
    float vp = 0.f;
    for (int i = tid; i < NF; i += 256) {
        float Q = fminf(fmaxf(pa[i], 0.f), 1.f);
        float P = (float)((double)i * stp) / (float)fs2;
        P = fminf(fmaxf(P, 0.f), 1.f);
        const float d = P - Q;
        vp += d * d;
    }
    #pragma unroll
    for (int off = 32; off > 0; off >>= 1) vp += __shfl_down(vp, off);
    if (lane == 0) red[wid] = vp;
    __syncthreads();
    if (tid == 0) {
        const float var = (red[0] + red[1] + red[2] + red[3]) / (float)NF;
        out[0] = (*gband) / (float)B + (*gsparse) / (float)B + var;
    }
}

extern "C" void kernel_launch(void* const* d_in, const int* in_sizes, int n_in,
                              void* d_out, int out_size, void* d_ws, size_t ws_size,
                              hipStream_t stream)
{
    const float* preds = (const float*)d_in[0];
    const int*   Fs    = (const int*)d_in[1];
    const int B = in_sizes[0] / NFFT;

    float* gpsd    = (float*)d_ws;
    float* gband   = gpsd + NF;
    float* gsparse = gband + 1;

    hipMemsetAsync(d_ws, 0, (NF + 2) * sizeof(float), stream);

    const int rpw    = 4;
    const int nwaves = (B + rpw - 1) / rpw;
    const int nblk   = (nwaves + 3) / 4;

    hipLaunchKernelGGL(k1, dim3(nblk), dim3(256), 0, stream,
                       preds, Fs, gpsd, gband, gsparse, B, rpw);
    hipLaunchKernelGGL(k2, dim3(1), dim3(256), 0, stream,
                       gpsd, gband, gsparse, Fs, (float*)d_out, B);
}